// Round 16
// baseline (433.258 us; speedup 1.0000x reference)
//
#include <hip/hip_runtime.h>
#include <cmath>

// N=50000 nodes, E=800000 edges, B=64 graphs, H=2 heads, D=128, FIN=128, L=2.

typedef __attribute__((ext_vector_type(8))) short short8v;   // 8 x bf16 (4 VGPRs)
typedef __attribute__((ext_vector_type(4))) float float4v;   // MFMA acc
typedef __attribute__((ext_vector_type(2))) float float2v;   // packed f32 pair

__device__ __forceinline__ float sigmoidf_(float x){ return 1.f/(1.f+expf(-x)); }
__device__ __forceinline__ float fexp(float x){ return __expf(x); }   // v_exp_f32 path

__device__ __forceinline__ unsigned f2bf_rne(float f){
  unsigned u = __float_as_uint(f);
  return (u + 0x7fffu + ((u >> 16) & 1u)) >> 16;   // round-nearest-even bf16
}
__device__ __forceinline__ float bf2f(ushort v){ return __uint_as_float((unsigned)v << 16); }
// fp8 e4m3 (hardware cvt, OCP on gfx950; encode+decode use the same HW format)
__device__ __forceinline__ unsigned char f2fp8(float f){
  unsigned v = __builtin_amdgcn_cvt_pk_fp8_f32(f, f, 0, false);
  return (unsigned char)(v & 0xffu);
}

// ---------------- CSR build (by dst) ----------------
__global__ void k_hist(const int* __restrict__ dst, int* __restrict__ deg, int E){
  int e = blockIdx.x*blockDim.x + threadIdx.x;
  if (e < E) atomicAdd(&deg[dst[e]], 1);
}

#define CHUNK 1024
__global__ __launch_bounds__(256) void k_chunksum(const int* __restrict__ in, int* __restrict__ csum, int n){
  int b = blockIdx.x;
  int tid = threadIdx.x;
  int v = 0;
  #pragma unroll
  for (int k = 0; k < 4; k++){
    int i = b*CHUNK + tid + k*256;
    if (i < n) v += in[i];
  }
  for (int d = 1; d < 64; d <<= 1) v += __shfl_xor(v, d);
  __shared__ int ws[4];
  if ((tid & 63) == 0) ws[tid>>6] = v;
  __syncthreads();
  if (tid == 0) csum[b] = ws[0]+ws[1]+ws[2]+ws[3];
}

// scan_apply with inlined small-scan of csum (nb <= 64); last block writes offs[n]
__global__ __launch_bounds__(256) void k_scan_apply(const int* __restrict__ in, const int* __restrict__ csum,
                                                    int* __restrict__ offs, int n, int nb){
  int b = blockIdx.x;
  int tid = threadIdx.x, lane = tid & 63, wid = tid >> 6;
  __shared__ int s_cpre;
  __shared__ int ws[4];
  if (tid < 64){
    int v = (tid < nb) ? csum[tid] : 0;
    int icl = v;
    for (int d = 1; d < 64; d <<= 1){ int t = __shfl_up(icl, d); if (lane >= d) icl += t; }
    if (tid == b) s_cpre = icl - v;
  }
  __syncthreads();
  int x[4];
  int s = 0;
  #pragma unroll
  for (int k = 0; k < 4; k++){
    int i = b*CHUNK + tid*4 + k;
    x[k] = (i < n) ? in[i] : 0;
    s += x[k];
  }
  int incl = s;
  for (int d = 1; d < 64; d <<= 1){ int t = __shfl_up(incl, d); if (lane >= d) incl += t; }
  if (lane == 63) ws[wid] = incl;
  __syncthreads();
  int wpre = 0;
  for (int w = 0; w < wid; w++) wpre += ws[w];
  int base = s_cpre + wpre + incl - s;
  #pragma unroll
  for (int k = 0; k < 4; k++){
    int i = b*CHUNK + tid*4 + k;
    if (i < n) offs[i] = base;
    base += x[k];
  }
  if (b == nb-1 && tid == 255) offs[n] = base;
}

// scatter src ids into CSR slot order (layer-invariant, built once)
__global__ void k_scatter_src(const int* __restrict__ src, const int* __restrict__ dst,
                              const int* __restrict__ offs, int* __restrict__ cnt,
                              int* __restrict__ srcP, int E){
  int e = blockIdx.x*blockDim.x + threadIdx.x;
  if (e < E){ int d = dst[e]; int p = atomicAdd(&cnt[d], 1); srcP[offs[d] + p] = src[e]; }
}

// ---------------- fused prep: graph_bounds + tobf16/gate0 + Wt transpose x3 + lstm prep ----------------
__global__ __launch_bounds__(256) void k_prep(
    const int* __restrict__ ng, int* __restrict__ gstart,
    const float* __restrict__ nfeats, const float* __restrict__ gw0, const float* __restrict__ gb0,
    ushort* __restrict__ xh0, float* __restrict__ gate,
    const float* __restrict__ W0, const float* __restrict__ W1, const float* __restrict__ W2,
    ushort* __restrict__ Wt,
    const float* __restrict__ Wih, const float* __restrict__ Whh,
    const float* __restrict__ bih, const float* __restrict__ bhh,
    unsigned* __restrict__ Wxp, unsigned* __restrict__ Whp, float* __restrict__ bias2,
    int N, int B){
  int tid = threadIdx.x;
  int blk = blockIdx.x;
  const int nbGB = (N + 255) >> 8;     // 196
  const int nbTG = (N + 3) >> 2;       // 12500
  const int nbWT = (3*256*128) >> 8;   // 384
  if (blk < nbGB){
    int i = blk*256 + tid;
    if (i >= N) return;
    int g = ng[i];
    int gp = (i == 0) ? -1 : ng[i-1];
    for (int bb = gp+1; bb <= g; bb++) gstart[bb] = i;
    if (i == N-1) for (int bb = g+1; bb <= B; bb++) gstart[bb] = N;
    return;
  }
  blk -= nbGB;
  if (blk < nbTG){
    int n = blk*4 + (tid >> 6);
    if (n >= N) return;
    int lane = tid & 63;
    float2 v = *(const float2*)(nfeats + (size_t)n*128 + lane*2);
    unsigned pk = (f2bf_rne(v.y) << 16) | f2bf_rne(v.x);
    *(unsigned*)(xh0 + (size_t)n*128 + lane*2) = pk;
    float2 gv = *(const float2*)(gw0 + lane*2);
    float p = v.x*gv.x + v.y*gv.y;
    for (int k = 1; k < 64; k <<= 1) p += __shfl_xor(p, k);
    if (lane == 0) gate[n] = p + gb0[0];
    return;
  }
  blk -= nbTG;
  if (blk < nbWT){
    int idx = blk*256 + tid;             // 0..98303
    int layer = idx >> 15;
    int within = idx & 32767;
    int c = within >> 7;
    int k = within & 127;
    const float* W = (layer == 0) ? W0 : (layer == 1) ? W1 : W2;
    Wt[idx] = (ushort)f2bf_rne(W[(size_t)k*256 + c]);
    return;
  }
  blk -= nbWT;
  {
    int idx = blk*256 + tid;             // 0..131071
    if (idx >= 131072) return;
    int j   = idx & 511;
    int c   = (idx >> 9) & 63;
    int isH = (idx >> 15) & 1;
    int l   = idx >> 16;
    const float* srcW = isH ? Whh : Wih;
    float w0 = srcW[(size_t)l*512*128 + (size_t)j*128 + 2*c];
    float w1 = srcW[(size_t)l*512*128 + (size_t)j*128 + 2*c + 1];
    unsigned v = (f2bf_rne(w1) << 16) | f2bf_rne(w0);
    unsigned* dstp = isH ? Whp : Wxp;
    dstp[(size_t)l*32768 + c*512 + j] = v;
    if (!isH && c == 0) bias2[l*512 + j] = bih[l*512 + j] + bhh[l*512 + j];
  }
}

// ---------------- fused MFMA GEMM (Wt in LDS) + pool-partial (independent roles) ----------------
// blocks [0, gemmBlocks): GEMM layer t. blocks [gemmBlocks, gemmBlocks+1024): pool stage t
// (64 graphs x 16, each block does 2 of 32 partials). Pool x == GEMM input (same buffer).
__global__ __launch_bounds__(256) void k_gemm_pool(const ushort* __restrict__ Xh,
    const ushort* __restrict__ Wt, const float* __restrict__ alv, const float* __restrict__ arv,
    unsigned char* __restrict__ Y8, float* __restrict__ el, float* __restrict__ er, int M,
    int gemmBlocks, const float* __restrict__ gate, const int* __restrict__ gstart,
    float* __restrict__ partials){
  __shared__ ushort WlS[16*256*8];   // 64 KB (gemm); aliased as f32 red[] by pool role
  int tid = threadIdx.x;
  if ((int)blockIdx.x < gemmBlocks){
    #pragma unroll
    for (int i = 0; i < 16; i++){
      int g = i*256 + tid;
      int row = g >> 4, c = g & 15;
      *(uint4*)(WlS + ((size_t)c*256 + row)*8) = *(const uint4*)(Wt + (size_t)row*128 + c*8);
    }
    __syncthreads();
    int wave = tid >> 6;
    int lane = tid & 63;
    int strip = blockIdx.x*4 + wave;
    if (strip*16 >= M) return;
    int m0 = strip*16;
    int l15 = lane & 15;
    int kg  = lane >> 4;
    int arow = m0 + l15; if (arow >= M) arow = M-1;
    short8v a[4];
    const ushort* xrow = Xh + (size_t)arow*128 + kg*8;
    #pragma unroll
    for (int ks = 0; ks < 4; ks++) a[ks] = *(const short8v*)(xrow + ks*32);
    float4v acc[16];
    #pragma unroll
    for (int nt = 0; nt < 16; nt++) acc[nt] = (float4v){0.f,0.f,0.f,0.f};
    #pragma unroll
    for (int nt = 0; nt < 16; nt++){
      #pragma unroll
      for (int ks = 0; ks < 4; ks++){
        short8v b = *(const short8v*)(WlS + (((size_t)(kg + ks*4)*256) + nt*16 + l15)*8);
        acc[nt] = __builtin_amdgcn_mfma_f32_16x16x32_bf16(a[ks], b, acc[nt], 0, 0, 0);
      }
    }
    float pel0[4]={0,0,0,0}, pel1[4]={0,0,0,0}, per0[4]={0,0,0,0}, per1[4]={0,0,0,0};
    #pragma unroll
    for (int nt = 0; nt < 16; nt++){
      int col = nt*16 + l15;
      float av = alv[col], rv = arv[col];
      #pragma unroll
      for (int j = 0; j < 4; j++){
        float v = acc[nt][j];
        int r = m0 + kg*4 + j;
        if (r < M) Y8[(size_t)r*256 + col] = f2fp8(v);
        if (nt < 8){ pel0[j] += v*av; per0[j] += v*rv; }
        else       { pel1[j] += v*av; per1[j] += v*rv; }
      }
    }
    #pragma unroll
    for (int j = 0; j < 4; j++){
      #pragma unroll
      for (int d = 1; d < 16; d <<= 1){
        pel0[j] += __shfl_xor(pel0[j], d);
        pel1[j] += __shfl_xor(pel1[j], d);
        per0[j] += __shfl_xor(per0[j], d);
        per1[j] += __shfl_xor(per1[j], d);
      }
    }
    if (l15 == 0){
      #pragma unroll
      for (int j = 0; j < 4; j++){
        int r = m0 + kg*4 + j;
        if (r < M){
          el[(size_t)r*2+0] = pel0[j];
          el[(size_t)r*2+1] = pel1[j];
          er[(size_t)r*2+0] = per0[j];
          er[(size_t)r*2+1] = per1[j];
        }
      }
    }
  } else {
    // pool role
    float* red = (float*)WlS;
    int pb = blockIdx.x - gemmBlocks;
    int b = pb >> 4;
    int py = pb & 15;
    int lane = tid & 63, wid = tid >> 6;
    int n0 = gstart[b], n1 = gstart[b+1];
    float m = -3.4e38f;
    for (int n = n0 + tid; n < n1; n += 256) m = fmaxf(m, gate[n]);
    for (int k = 1; k < 64; k <<= 1) m = fmaxf(m, __shfl_xor(m, k));
    if (lane == 0) red[wid] = m;
    __syncthreads();
    m = fmaxf(fmaxf(red[0], red[1]), fmaxf(red[2], red[3]));
    __syncthreads();
    float s = 0.f;
    for (int n = n0 + tid; n < n1; n += 256) s += __expf(gate[n] - m);
    for (int k = 1; k < 64; k <<= 1) s += __shfl_xor(s, k);
    if (lane == 0) red[wid] = s;
    __syncthreads();
    s = red[0] + red[1] + red[2] + red[3];
    float inv = (s > 0.f) ? 1.f/s : 0.f;
    int half = tid >> 7, t127 = tid & 127;
    int p = py*2 + half;
    float acc = 0.f;
    for (int n = n0 + p; n < n1; n += 32){
      float w = __expf(gate[n] - m) * inv;
      acc += w * bf2f(Xh[(size_t)n*128 + t127]);
    }
    partials[((size_t)b*32 + p)*128 + t127] = acc;
  }
}

// ---------------- softmax + aggregate (in-kernel scores, fp8 gather, 4 edges/iter, 16B/lane) ----------------
#define MAXE 256
__global__ __launch_bounds__(256) void k_aggregate(const unsigned char* __restrict__ hpair8,
    const float* __restrict__ el, const float* __restrict__ er,
    const int* __restrict__ srcP, const int* __restrict__ offs,
    const float* __restrict__ bias, const float* __restrict__ gwv, const float* __restrict__ gbv,
    ushort* __restrict__ outh, float* __restrict__ gate, int Nn){
  __shared__ float sw[4][MAXE][2];   // scores -> unnormalized exp weights (8 KB)
  __shared__ int   ss[4][MAXE];      // src ids (4 KB)
  int wave = threadIdx.x >> 6;
  int n = blockIdx.x*4 + wave;
  if (n >= Nn) return;
  int lane = threadIdx.x & 63;
  int e0 = offs[n], e1 = offs[n+1];
  int deg = e1 - e0;
  int quarter = lane >> 4;     // which edge of the 4-pack
  int sub     = lane & 15;     // 16-dim slice of flat 256
  int head    = sub >> 3;
  float2 erv = *(const float2*)(er + (size_t)n*2);
  float2v acc[8];
  #pragma unroll
  for (int k = 0; k < 8; k++) acc[k] = (float2v){0.f, 0.f};
  float inv0, inv1;

  if (deg <= MAXE){
    float m0 = -3.4e38f, m1 = -3.4e38f;
    for (int i = lane; i < deg; i += 64){
      int s = srcP[e0 + i];
      ss[wave][i] = s;
      float2 lv = *(const float2*)(el + (size_t)s*2);
      float v0 = lv.x + erv.x, v1 = lv.y + erv.y;
      v0 = (v0 > 0.f) ? v0 : 0.2f*v0;
      v1 = (v1 > 0.f) ? v1 : 0.2f*v1;
      sw[wave][i][0] = v0; sw[wave][i][1] = v1;
      m0 = fmaxf(m0, v0); m1 = fmaxf(m1, v1);
    }
    for (int k = 1; k < 64; k <<= 1){ m0 = fmaxf(m0, __shfl_xor(m0, k)); m1 = fmaxf(m1, __shfl_xor(m1, k)); }
    float s0 = 0.f, s1 = 0.f;
    for (int i = lane; i < deg; i += 64){
      float x0 = fexp(sw[wave][i][0] - m0);
      float x1 = fexp(sw[wave][i][1] - m1);
      sw[wave][i][0] = x0; sw[wave][i][1] = x1;
      s0 += x0; s1 += x1;
    }
    for (int k = 1; k < 64; k <<= 1){ s0 += __shfl_xor(s0, k); s1 += __shfl_xor(s1, k); }
    inv0 = (s0 > 0.f) ? 1.f/s0 : 0.f;
    inv1 = (s1 > 0.f) ? 1.f/s1 : 0.f;
    for (int i = quarter; i < deg; i += 4){
      int s = ss[wave][i];
      float w = sw[wave][i][head];
      uint4 hv = *(const uint4*)(hpair8 + (size_t)s*256 + sub*16);
      float2v wv = { w, w };
      acc[0] += wv*__builtin_amdgcn_cvt_pk_f32_fp8(hv.x, false);
      acc[1] += wv*__builtin_amdgcn_cvt_pk_f32_fp8(hv.x, true);
      acc[2] += wv*__builtin_amdgcn_cvt_pk_f32_fp8(hv.y, false);
      acc[3] += wv*__builtin_amdgcn_cvt_pk_f32_fp8(hv.y, true);
      acc[4] += wv*__builtin_amdgcn_cvt_pk_f32_fp8(hv.z, false);
      acc[5] += wv*__builtin_amdgcn_cvt_pk_f32_fp8(hv.z, true);
      acc[6] += wv*__builtin_amdgcn_cvt_pk_f32_fp8(hv.w, false);
      acc[7] += wv*__builtin_amdgcn_cvt_pk_f32_fp8(hv.w, true);
    }
  } else {
    float m0 = -3.4e38f, m1 = -3.4e38f;
    for (int i = e0 + lane; i < e1; i += 64){
      int s = srcP[i];
      float2 lv = *(const float2*)(el + (size_t)s*2);
      float v0 = lv.x + erv.x, v1 = lv.y + erv.y;
      v0 = (v0 > 0.f) ? v0 : 0.2f*v0;
      v1 = (v1 > 0.f) ? v1 : 0.2f*v1;
      m0 = fmaxf(m0, v0); m1 = fmaxf(m1, v1);
    }
    for (int k = 1; k < 64; k <<= 1){ m0 = fmaxf(m0, __shfl_xor(m0, k)); m1 = fmaxf(m1, __shfl_xor(m1, k)); }
    float s0 = 0.f, s1 = 0.f;
    for (int i = e0 + lane; i < e1; i += 64){
      int s = srcP[i];
      float2 lv = *(const float2*)(el + (size_t)s*2);
      float v0 = lv.x + erv.x, v1 = lv.y + erv.y;
      v0 = (v0 > 0.f) ? v0 : 0.2f*v0;
      v1 = (v1 > 0.f) ? v1 : 0.2f*v1;
      s0 += fexp(v0 - m0); s1 += fexp(v1 - m1);
    }
    for (int k = 1; k < 64; k <<= 1){ s0 += __shfl_xor(s0, k); s1 += __shfl_xor(s1, k); }
    inv0 = (s0 > 0.f) ? 1.f/s0 : 0.f;
    inv1 = (s1 > 0.f) ? 1.f/s1 : 0.f;
    for (int c0 = e0; c0 < e1; c0 += 64){
      int ce = e1 - c0; if (ce > 64) ce = 64;
      if (lane < ce){
        int s = srcP[c0 + lane];
        float2 lv = *(const float2*)(el + (size_t)s*2);
        float v0 = lv.x + erv.x, v1 = lv.y + erv.y;
        v0 = (v0 > 0.f) ? v0 : 0.2f*v0;
        v1 = (v1 > 0.f) ? v1 : 0.2f*v1;
        ss[wave][lane] = s;
        sw[wave][lane][0] = fexp(v0 - m0);
        sw[wave][lane][1] = fexp(v1 - m1);
      }
      for (int i = quarter; i < ce; i += 4){
        int s = ss[wave][i];
        float w = sw[wave][i][head];
        uint4 hv = *(const uint4*)(hpair8 + (size_t)s*256 + sub*16);
        float2v wv = { w, w };
        acc[0] += wv*__builtin_amdgcn_cvt_pk_f32_fp8(hv.x, false);
        acc[1] += wv*__builtin_amdgcn_cvt_pk_f32_fp8(hv.x, true);
        acc[2] += wv*__builtin_amdgcn_cvt_pk_f32_fp8(hv.y, false);
        acc[3] += wv*__builtin_amdgcn_cvt_pk_f32_fp8(hv.y, true);
        acc[4] += wv*__builtin_amdgcn_cvt_pk_f32_fp8(hv.z, false);
        acc[5] += wv*__builtin_amdgcn_cvt_pk_f32_fp8(hv.z, true);
        acc[6] += wv*__builtin_amdgcn_cvt_pk_f32_fp8(hv.w, false);
        acc[7] += wv*__builtin_amdgcn_cvt_pk_f32_fp8(hv.w, true);
      }
    }
  }

  // sum the 4 quarter-partials (xor 16/32 preserves sub -> same head), then normalize
  float inv = head ? inv1 : inv0;
  #pragma unroll
  for (int k = 0; k < 8; k++){
    float2v t16, t32;
    t16[0] = __shfl_xor(acc[k][0], 16); t16[1] = __shfl_xor(acc[k][1], 16);
    acc[k] += t16;
    t32[0] = __shfl_xor(acc[k][0], 32); t32[1] = __shfl_xor(acc[k][1], 32);
    acc[k] += t32;
  }
  float t[16];
  #pragma unroll
  for (int k = 0; k < 16; k++)
    t[k] = fmaxf(acc[k>>1][k&1]*inv + bias[sub*16 + k], 0.f);
  float o[16];
  #pragma unroll
  for (int k = 0; k < 16; k++) o[k] = 0.5f*(t[k] + __shfl_xor(t[k], 8));
  if (lane < 8){
    ushort u[16];
    #pragma unroll
    for (int k = 0; k < 16; k++) u[k] = (ushort)f2bf_rne(o[k]);
    *(uint4*)(outh + (size_t)n*128 + sub*16)     = *(uint4*)u;
    *(uint4*)(outh + (size_t)n*128 + sub*16 + 8) = *(uint4*)(u + 8);
    float gp = 0.f;
    #pragma unroll
    for (int k = 0; k < 16; k++) gp += o[k]*gwv[sub*16 + k];
    #pragma unroll
    for (int d = 1; d < 8; d <<= 1) gp += __shfl_xor(gp, d);
    if (sub == 0) gate[n] = gp + gbv[0];
  }
}

// ---------------- fused LSTM: seq = reduce(partials4), 2 layers x 4 steps + final head ----------------
__global__ __launch_bounds__(512) void k_lstm_all(const float* __restrict__ part4,
    const unsigned* __restrict__ Wxp, const unsigned* __restrict__ Whp,
    const float* __restrict__ bias2,
    const float* __restrict__ cw, const float* __restrict__ cb,
    float* __restrict__ out, int B){
  int b = blockIdx.x;
  int j = threadIdx.x;
  __shared__ float xs[4][128];
  __shared__ float gates[512];
  __shared__ float hcur[128], ccur[128];
  __shared__ float l0out[4][128];
  __shared__ float red[2];

  #pragma unroll
  for (int l = 0; l < 2; l++){
    const unsigned* Wx = Wxp + (size_t)l*32768;
    const unsigned* Wh = Whp + (size_t)l*32768;
    const float* bi = bias2 + l*512;
    { int t = j >> 7, k = j & 127;
      if (l == 0){
        const float* pp = part4 + (((size_t)t*B + b)*32)*128 + k;
        float s = 0.f;
        #pragma unroll
        for (int p2 = 0; p2 < 32; p2++) s += pp[p2*128];
        xs[t][k] = s;
      } else {
        xs[t][k] = l0out[t][k];
      }
      if (j < 128){ hcur[j] = 0.f; ccur[j] = 0.f; } }
    __syncthreads();
    float gx[4] = {0.f, 0.f, 0.f, 0.f};
    #pragma unroll 8
    for (int c = 0; c < 64; c++){
      unsigned w2 = Wx[c*512 + j];
      float wlo = __uint_as_float(w2 << 16);
      float whi = __uint_as_float(w2 & 0xffff0000u);
      #pragma unroll
      for (int t = 0; t < 4; t++)
        gx[t] += xs[t][2*c]*wlo + xs[t][2*c+1]*whi;
    }
    #pragma unroll
    for (int t = 0; t < 4; t++){
      float g = gx[t] + bi[j];
      #pragma unroll 8
      for (int c = 0; c < 64; c++){
        unsigned w2 = Wh[c*512 + j];
        g += hcur[2*c]*__uint_as_float(w2 << 16)
           + hcur[2*c+1]*__uint_as_float(w2 & 0xffff0000u);
      }
      gates[j] = g;
      __syncthreads();
      if (j < 128){
        float gi = sigmoidf_(gates[j]);
        float gf = sigmoidf_(gates[128 + j]);
        float gg = tanhf(gates[256 + j]);
        float go = sigmoidf_(gates[384 + j]);
        float c2 = gf * ccur[j] + gi * gg;
        float h = go * tanhf(c2);
        ccur[j] = c2;
        hcur[j] = h;
        if (l == 0) l0out[t][j] = h;
      }
      __syncthreads();
    }
  }
  float p = (j < 128) ? hcur[j] * cw[j] : 0.f;
  if (j < 128){
    for (int k = 1; k < 64; k <<= 1) p += __shfl_xor(p, k);
    if ((j & 63) == 0) red[j >> 6] = p;
  }
  __syncthreads();
  if (j == 0) out[b] = sigmoidf_(red[0] + red[1] + cb[0]);
}

extern "C" void kernel_launch(void* const* d_in, const int* in_sizes, int n_in,
                              void* d_out, int out_size, void* d_ws, size_t ws_size,
                              hipStream_t stream){
  const float* nfeats = (const float*)d_in[0];
  const int*   src    = (const int*)d_in[1];
  const int*   dst    = (const int*)d_in[2];
  const int*   ng     = (const int*)d_in[3];
  const float* Wm[3]  = { (const float*)d_in[4],  (const float*)d_in[8],  (const float*)d_in[12] };
  const float* al[3]  = { (const float*)d_in[5],  (const float*)d_in[9],  (const float*)d_in[13] };
  const float* ar[3]  = { (const float*)d_in[6],  (const float*)d_in[10], (const float*)d_in[14] };
  const float* bb[3]  = { (const float*)d_in[7],  (const float*)d_in[11], (const float*)d_in[15] };
  const float* gw[4]  = { (const float*)d_in[16], (const float*)d_in[18], (const float*)d_in[20], (const float*)d_in[22] };
  const float* gb[4]  = { (const float*)d_in[17], (const float*)d_in[19], (const float*)d_in[21], (const float*)d_in[23] };
  const float* Wih = (const float*)d_in[24];
  const float* Whh = (const float*)d_in[25];
  const float* bih = (const float*)d_in[26];
  const float* bhh = (const float*)d_in[27];
  const float* cw  = (const float*)d_in[28];
  const float* cb  = (const float*)d_in[29];

  const int N = in_sizes[3];      // 50000
  const int E = in_sizes[1];      // 800000
  const int B = out_size;         // 64

  char* p = (char*)d_ws;
  auto alloc = [&](size_t bytes) -> void* {
    void* q = (void*)p;
    p += (bytes + 255) & ~(size_t)255;
    return q;
  };
  unsigned char* hpair8 = (unsigned char*)alloc((size_t)N*256);
  ushort* aggh   = (ushort*)alloc((size_t)N*128*2);
  ushort* xh0    = (ushort*)alloc((size_t)N*128*2);
  ushort* Wt     = (ushort*)alloc((size_t)3*256*128*2);
  float*  el     = (float*)alloc((size_t)N*2*4);
  float*  er     = (float*)alloc((size_t)N*2*4);
  int*    srcP   = (int*)alloc((size_t)E*4);
  float*  gate   = (float*)alloc((size_t)N*4);
  int*    deg    = (int*)alloc((size_t)N*4);
  int*    cnt    = (int*)alloc((size_t)N*4);     // adjacent to deg: one memset
  int*    offs   = (int*)alloc((size_t)(N+1)*4);
  int*    gstart = (int*)alloc((size_t)(B+1)*4);
  int*    csum   = (int*)alloc((size_t)64*4);
  float*  part4  = (float*)alloc((size_t)4*B*32*128*4);   // 4 pool stages
  unsigned* Wxp  = (unsigned*)alloc((size_t)2*64*512*4);
  unsigned* Whp  = (unsigned*)alloc((size_t)2*64*512*4);
  float*  bias2  = (float*)alloc((size_t)2*512*4);

  auto cdiv = [](int a, int b){ return (a + b - 1) / b; };
  const int NB = cdiv(N, CHUNK);   // 49 chunks

  // one memset covers deg + pad + cnt
  hipMemsetAsync(deg, 0, (size_t)((char*)cnt - (char*)deg) + (size_t)N*4, stream);
  k_hist<<<cdiv(E,256), 256, 0, stream>>>(dst, deg, E);
  k_chunksum<<<NB, 256, 0, stream>>>(deg, csum, N);
  k_scan_apply<<<NB, 256, 0, stream>>>(deg, csum, offs, N, NB);
  k_scatter_src<<<cdiv(E,256), 256, 0, stream>>>(src, dst, offs, cnt, srcP, E);

  {
    int nbGB = cdiv(N,256), nbTG = cdiv(N,4), nbWT = (3*256*128)/256, nbLP = cdiv(131072,256);
    k_prep<<<nbGB + nbTG + nbWT + nbLP, 256, 0, stream>>>(
        ng, gstart, nfeats, gw[0], gb[0], xh0, gate,
        Wm[0], Wm[1], Wm[2], Wt, Wih, Whh, bih, bhh, Wxp, Whp, bias2, N, B);
  }

  const int strips = cdiv(N, 16);
  const int gemmBlocks = cdiv(strips, 4);   // 782
  const int poolBlocks = B*16;              // 1024

  const ushort* xh = xh0;
  for (int layer = 0; layer < 3; layer++){
    // fused: GEMM layer + pool stage `layer` (pool x == gemm input, gate from previous stage)
    k_gemm_pool<<<gemmBlocks + poolBlocks, 256, 0, stream>>>(xh, Wt + (size_t)layer*256*128,
        al[layer], ar[layer], hpair8, el, er, N, gemmBlocks, gate, gstart,
        part4 + (size_t)layer*B*32*128);
    k_aggregate<<<cdiv(N,4), 256, 0, stream>>>(hpair8, el, er, srcP, offs,
        bb[layer], gw[layer+1], gb[layer+1], aggh, gate, N);
    xh = aggh;
  }
  // pool stage 3 (no gemm role)
  k_gemm_pool<<<poolBlocks, 256, 0, stream>>>(aggh, Wt, al[0], ar[0], hpair8, el, er, N,
      0, gate, gstart, part4 + (size_t)3*B*32*128);

  k_lstm_all<<<B, 512, 0, stream>>>(part4, Wxp, Whp, bias2, cw, cb, (float*)d_out, B);
}

// Round 17
// 390.464 us; speedup vs baseline: 1.1096x; 1.1096x over previous
//
#include <hip/hip_runtime.h>
#include <cmath>

// N=50000 nodes, E=800000 edges, B=64 graphs, H=2 heads, D=128, FIN=128, L=2.

typedef __attribute__((ext_vector_type(8))) short short8v;   // 8 x bf16 (4 VGPRs)
typedef __attribute__((ext_vector_type(4))) float float4v;   // MFMA acc
typedef __attribute__((ext_vector_type(2))) float float2v;   // packed f32 pair

__device__ __forceinline__ float sigmoidf_(float x){ return 1.f/(1.f+expf(-x)); }
__device__ __forceinline__ float fexp(float x){ return __expf(x); }   // v_exp_f32 path

__device__ __forceinline__ unsigned f2bf_rne(float f){
  unsigned u = __float_as_uint(f);
  return (u + 0x7fffu + ((u >> 16) & 1u)) >> 16;   // round-nearest-even bf16
}
__device__ __forceinline__ float bf2f(ushort v){ return __uint_as_float((unsigned)v << 16); }
// fp8 e4m3 (hardware cvt, OCP on gfx950; encode+decode use the same HW format)
__device__ __forceinline__ unsigned char f2fp8(float f){
  unsigned v = __builtin_amdgcn_cvt_pk_fp8_f32(f, f, 0, false);
  return (unsigned char)(v & 0xffu);
}

// ---------------- CSR build (by dst) ----------------
__global__ void k_hist(const int* __restrict__ dst, int* __restrict__ deg, int E){
  int e = blockIdx.x*blockDim.x + threadIdx.x;
  if (e < E) atomicAdd(&deg[dst[e]], 1);
}

#define CHUNK 1024
__global__ __launch_bounds__(256) void k_chunksum(const int* __restrict__ in, int* __restrict__ csum, int n){
  int b = blockIdx.x;
  int tid = threadIdx.x;
  int v = 0;
  #pragma unroll
  for (int k = 0; k < 4; k++){
    int i = b*CHUNK + tid + k*256;
    if (i < n) v += in[i];
  }
  for (int d = 1; d < 64; d <<= 1) v += __shfl_xor(v, d);
  __shared__ int ws[4];
  if ((tid & 63) == 0) ws[tid>>6] = v;
  __syncthreads();
  if (tid == 0) csum[b] = ws[0]+ws[1]+ws[2]+ws[3];
}

// scan_apply with inlined small-scan of csum (nb <= 64); last block writes offs[n]
__global__ __launch_bounds__(256) void k_scan_apply(const int* __restrict__ in, const int* __restrict__ csum,
                                                    int* __restrict__ offs, int n, int nb){
  int b = blockIdx.x;
  int tid = threadIdx.x, lane = tid & 63, wid = tid >> 6;
  __shared__ int s_cpre;
  __shared__ int ws[4];
  if (tid < 64){
    int v = (tid < nb) ? csum[tid] : 0;
    int icl = v;
    for (int d = 1; d < 64; d <<= 1){ int t = __shfl_up(icl, d); if (lane >= d) icl += t; }
    if (tid == b) s_cpre = icl - v;
  }
  __syncthreads();
  int x[4];
  int s = 0;
  #pragma unroll
  for (int k = 0; k < 4; k++){
    int i = b*CHUNK + tid*4 + k;
    x[k] = (i < n) ? in[i] : 0;
    s += x[k];
  }
  int incl = s;
  for (int d = 1; d < 64; d <<= 1){ int t = __shfl_up(incl, d); if (lane >= d) incl += t; }
  if (lane == 63) ws[wid] = incl;
  __syncthreads();
  int wpre = 0;
  for (int w = 0; w < wid; w++) wpre += ws[w];
  int base = s_cpre + wpre + incl - s;
  #pragma unroll
  for (int k = 0; k < 4; k++){
    int i = b*CHUNK + tid*4 + k;
    if (i < n) offs[i] = base;
    base += x[k];
  }
  if (b == nb-1 && tid == 255) offs[n] = base;
}

// scatter src ids into CSR slot order (layer-invariant, built once)
__global__ void k_scatter_src(const int* __restrict__ src, const int* __restrict__ dst,
                              const int* __restrict__ offs, int* __restrict__ cnt,
                              int* __restrict__ srcP, int E){
  int e = blockIdx.x*blockDim.x + threadIdx.x;
  if (e < E){ int d = dst[e]; int p = atomicAdd(&cnt[d], 1); srcP[offs[d] + p] = src[e]; }
}

// ---------------- fused prep: graph_bounds + tobf16/gate0 + Wt transpose x3 + lstm prep ----------------
__global__ __launch_bounds__(256) void k_prep(
    const int* __restrict__ ng, int* __restrict__ gstart,
    const float* __restrict__ nfeats, const float* __restrict__ gw0, const float* __restrict__ gb0,
    ushort* __restrict__ xh0, float* __restrict__ gate,
    const float* __restrict__ W0, const float* __restrict__ W1, const float* __restrict__ W2,
    ushort* __restrict__ Wt,
    const float* __restrict__ Wih, const float* __restrict__ Whh,
    const float* __restrict__ bih, const float* __restrict__ bhh,
    unsigned* __restrict__ Wxp, unsigned* __restrict__ Whp, float* __restrict__ bias2,
    int N, int B){
  int tid = threadIdx.x;
  int blk = blockIdx.x;
  const int nbGB = (N + 255) >> 8;
  const int nbTG = (N + 3) >> 2;
  const int nbWT = (3*256*128) >> 8;
  if (blk < nbGB){
    int i = blk*256 + tid;
    if (i >= N) return;
    int g = ng[i];
    int gp = (i == 0) ? -1 : ng[i-1];
    for (int bb = gp+1; bb <= g; bb++) gstart[bb] = i;
    if (i == N-1) for (int bb = g+1; bb <= B; bb++) gstart[bb] = N;
    return;
  }
  blk -= nbGB;
  if (blk < nbTG){
    int n = blk*4 + (tid >> 6);
    if (n >= N) return;
    int lane = tid & 63;
    float2 v = *(const float2*)(nfeats + (size_t)n*128 + lane*2);
    unsigned pk = (f2bf_rne(v.y) << 16) | f2bf_rne(v.x);
    *(unsigned*)(xh0 + (size_t)n*128 + lane*2) = pk;
    float2 gv = *(const float2*)(gw0 + lane*2);
    float p = v.x*gv.x + v.y*gv.y;
    for (int k = 1; k < 64; k <<= 1) p += __shfl_xor(p, k);
    if (lane == 0) gate[n] = p + gb0[0];
    return;
  }
  blk -= nbTG;
  if (blk < nbWT){
    int idx = blk*256 + tid;
    int layer = idx >> 15;
    int within = idx & 32767;
    int c = within >> 7;
    int k = within & 127;
    const float* W = (layer == 0) ? W0 : (layer == 1) ? W1 : W2;
    Wt[idx] = (ushort)f2bf_rne(W[(size_t)k*256 + c]);
    return;
  }
  blk -= nbWT;
  {
    int idx = blk*256 + tid;
    if (idx >= 131072) return;
    int j   = idx & 511;
    int c   = (idx >> 9) & 63;
    int isH = (idx >> 15) & 1;
    int l   = idx >> 16;
    const float* srcW = isH ? Whh : Wih;
    float w0 = srcW[(size_t)l*512*128 + (size_t)j*128 + 2*c];
    float w1 = srcW[(size_t)l*512*128 + (size_t)j*128 + 2*c + 1];
    unsigned v = (f2bf_rne(w1) << 16) | f2bf_rne(w0);
    unsigned* dstp = isH ? Whp : Wxp;
    dstp[(size_t)l*32768 + c*512 + j] = v;
    if (!isH && c == 0) bias2[l*512 + j] = bih[l*512 + j] + bhh[l*512 + j];
  }
}

// ---------------- MFMA GEMM (Wt staged in LDS): Y8[M,256](fp8) = Xh[M,128] @ W, fused el/er ----------------
__global__ __launch_bounds__(256) void k_gemm_mfma(const ushort* __restrict__ Xh,
    const ushort* __restrict__ Wt, const float* __restrict__ alv, const float* __restrict__ arv,
    unsigned char* __restrict__ Y8, float* __restrict__ el, float* __restrict__ er, int M){
  __shared__ ushort WlS[16*256*8];   // 64 KB
  int tid = threadIdx.x;
  #pragma unroll
  for (int i = 0; i < 16; i++){
    int g = i*256 + tid;
    int row = g >> 4, c = g & 15;
    *(uint4*)(WlS + ((size_t)c*256 + row)*8) = *(const uint4*)(Wt + (size_t)row*128 + c*8);
  }
  __syncthreads();
  int wave = tid >> 6;
  int lane = tid & 63;
  int strip = blockIdx.x*4 + wave;
  if (strip*16 >= M) return;
  int m0 = strip*16;
  int l15 = lane & 15;
  int kg  = lane >> 4;
  int arow = m0 + l15; if (arow >= M) arow = M-1;
  short8v a[4];
  const ushort* xrow = Xh + (size_t)arow*128 + kg*8;
  #pragma unroll
  for (int ks = 0; ks < 4; ks++) a[ks] = *(const short8v*)(xrow + ks*32);
  float4v acc[16];
  #pragma unroll
  for (int nt = 0; nt < 16; nt++) acc[nt] = (float4v){0.f,0.f,0.f,0.f};
  #pragma unroll
  for (int nt = 0; nt < 16; nt++){
    #pragma unroll
    for (int ks = 0; ks < 4; ks++){
      short8v b = *(const short8v*)(WlS + (((size_t)(kg + ks*4)*256) + nt*16 + l15)*8);
      acc[nt] = __builtin_amdgcn_mfma_f32_16x16x32_bf16(a[ks], b, acc[nt], 0, 0, 0);
    }
  }
  float pel0[4]={0,0,0,0}, pel1[4]={0,0,0,0}, per0[4]={0,0,0,0}, per1[4]={0,0,0,0};
  #pragma unroll
  for (int nt = 0; nt < 16; nt++){
    int col = nt*16 + l15;
    float av = alv[col], rv = arv[col];
    #pragma unroll
    for (int j = 0; j < 4; j++){
      float v = acc[nt][j];
      int r = m0 + kg*4 + j;
      if (r < M) Y8[(size_t)r*256 + col] = f2fp8(v);
      if (nt < 8){ pel0[j] += v*av; per0[j] += v*rv; }
      else       { pel1[j] += v*av; per1[j] += v*rv; }
    }
  }
  #pragma unroll
  for (int j = 0; j < 4; j++){
    #pragma unroll
    for (int d = 1; d < 16; d <<= 1){
      pel0[j] += __shfl_xor(pel0[j], d);
      pel1[j] += __shfl_xor(pel1[j], d);
      per0[j] += __shfl_xor(per0[j], d);
      per1[j] += __shfl_xor(per1[j], d);
    }
  }
  if (l15 == 0){
    #pragma unroll
    for (int j = 0; j < 4; j++){
      int r = m0 + kg*4 + j;
      if (r < M){
        el[(size_t)r*2+0] = pel0[j];
        el[(size_t)r*2+1] = pel1[j];
        er[(size_t)r*2+0] = per0[j];
        er[(size_t)r*2+1] = per1[j];
      }
    }
  }
}

// ---------------- aggregate (+ riding pool-partial blocks) ----------------
// blocks [0, nAgg): softmax+aggregate (round-15 logic, double-buffered gate out).
// blocks [nAgg, nAgg+1024): pool stage partials for (poolX, poolGate) -> partials.
// poolX/poolGate are PREVIOUS-stage buffers (different from outh/gateOut) => no race.
#define MAXE 256
__global__ __launch_bounds__(256) void k_agg_pool(const unsigned char* __restrict__ hpair8,
    const float* __restrict__ el, const float* __restrict__ er,
    const int* __restrict__ srcP, const int* __restrict__ offs,
    const float* __restrict__ bias, const float* __restrict__ gwv, const float* __restrict__ gbv,
    ushort* __restrict__ outh, float* __restrict__ gateOut, int Nn, int nAgg,
    const ushort* __restrict__ poolX, const float* __restrict__ poolGate,
    const int* __restrict__ gstart, float* __restrict__ partials){
  __shared__ float sw[4][MAXE][2];   // weights (8 KB); pool role reuses as red[]
  __shared__ int   ss[4][MAXE];      // src ids (4 KB)
  int tid = threadIdx.x;
  if ((int)blockIdx.x >= nAgg){
    // ---- pool-partial role ----
    float* red = (float*)sw;
    int pb = blockIdx.x - nAgg;
    int b = pb >> 4;
    int py = pb & 15;
    int lane = tid & 63, wid = tid >> 6;
    int n0 = gstart[b], n1 = gstart[b+1];
    float m = -3.4e38f;
    for (int n = n0 + tid; n < n1; n += 256) m = fmaxf(m, poolGate[n]);
    for (int k = 1; k < 64; k <<= 1) m = fmaxf(m, __shfl_xor(m, k));
    if (lane == 0) red[wid] = m;
    __syncthreads();
    m = fmaxf(fmaxf(red[0], red[1]), fmaxf(red[2], red[3]));
    __syncthreads();
    float s = 0.f;
    for (int n = n0 + tid; n < n1; n += 256) s += __expf(poolGate[n] - m);
    for (int k = 1; k < 64; k <<= 1) s += __shfl_xor(s, k);
    if (lane == 0) red[wid] = s;
    __syncthreads();
    s = red[0] + red[1] + red[2] + red[3];
    float inv = (s > 0.f) ? 1.f/s : 0.f;
    int half = tid >> 7, t127 = tid & 127;
    int p = py*2 + half;
    float acc = 0.f;
    for (int n = n0 + p; n < n1; n += 32){
      float w = __expf(poolGate[n] - m) * inv;
      acc += w * bf2f(poolX[(size_t)n*128 + t127]);
    }
    partials[((size_t)b*32 + p)*128 + t127] = acc;
    return;
  }
  // ---- aggregate role ----
  int wave = tid >> 6;
  int n = blockIdx.x*4 + wave;
  if (n >= Nn) return;
  int lane = tid & 63;
  int e0 = offs[n], e1 = offs[n+1];
  int deg = e1 - e0;
  int quarter = lane >> 4;
  int sub     = lane & 15;
  int head    = sub >> 3;
  float2 erv = *(const float2*)(er + (size_t)n*2);
  float2v acc[8];
  #pragma unroll
  for (int k = 0; k < 8; k++) acc[k] = (float2v){0.f, 0.f};
  float inv0, inv1;

  if (deg <= MAXE){
    float m0 = -3.4e38f, m1 = -3.4e38f;
    for (int i = lane; i < deg; i += 64){
      int s = srcP[e0 + i];
      ss[wave][i] = s;
      float2 lv = *(const float2*)(el + (size_t)s*2);
      float v0 = lv.x + erv.x, v1 = lv.y + erv.y;
      v0 = (v0 > 0.f) ? v0 : 0.2f*v0;
      v1 = (v1 > 0.f) ? v1 : 0.2f*v1;
      sw[wave][i][0] = v0; sw[wave][i][1] = v1;
      m0 = fmaxf(m0, v0); m1 = fmaxf(m1, v1);
    }
    for (int k = 1; k < 64; k <<= 1){ m0 = fmaxf(m0, __shfl_xor(m0, k)); m1 = fmaxf(m1, __shfl_xor(m1, k)); }
    float s0 = 0.f, s1 = 0.f;
    for (int i = lane; i < deg; i += 64){
      float x0 = fexp(sw[wave][i][0] - m0);
      float x1 = fexp(sw[wave][i][1] - m1);
      sw[wave][i][0] = x0; sw[wave][i][1] = x1;
      s0 += x0; s1 += x1;
    }
    for (int k = 1; k < 64; k <<= 1){ s0 += __shfl_xor(s0, k); s1 += __shfl_xor(s1, k); }
    inv0 = (s0 > 0.f) ? 1.f/s0 : 0.f;
    inv1 = (s1 > 0.f) ? 1.f/s1 : 0.f;
    for (int i = quarter; i < deg; i += 4){
      int s = ss[wave][i];
      float w = sw[wave][i][head];
      uint4 hv = *(const uint4*)(hpair8 + (size_t)s*256 + sub*16);
      float2v wv = { w, w };
      acc[0] += wv*__builtin_amdgcn_cvt_pk_f32_fp8(hv.x, false);
      acc[1] += wv*__builtin_amdgcn_cvt_pk_f32_fp8(hv.x, true);
      acc[2] += wv*__builtin_amdgcn_cvt_pk_f32_fp8(hv.y, false);
      acc[3] += wv*__builtin_amdgcn_cvt_pk_f32_fp8(hv.y, true);
      acc[4] += wv*__builtin_amdgcn_cvt_pk_f32_fp8(hv.z, false);
      acc[5] += wv*__builtin_amdgcn_cvt_pk_f32_fp8(hv.z, true);
      acc[6] += wv*__builtin_amdgcn_cvt_pk_f32_fp8(hv.w, false);
      acc[7] += wv*__builtin_amdgcn_cvt_pk_f32_fp8(hv.w, true);
    }
  } else {
    float m0 = -3.4e38f, m1 = -3.4e38f;
    for (int i = e0 + lane; i < e1; i += 64){
      int s = srcP[i];
      float2 lv = *(const float2*)(el + (size_t)s*2);
      float v0 = lv.x + erv.x, v1 = lv.y + erv.y;
      v0 = (v0 > 0.f) ? v0 : 0.2f*v0;
      v1 = (v1 > 0.f) ? v1 : 0.2f*v1;
      m0 = fmaxf(m0, v0); m1 = fmaxf(m1, v1);
    }
    for (int k = 1; k < 64; k <<= 1){ m0 = fmaxf(m0, __shfl_xor(m0, k)); m1 = fmaxf(m1, __shfl_xor(m1, k)); }
    float s0 = 0.f, s1 = 0.f;
    for (int i = e0 + lane; i < e1; i += 64){
      int s = srcP[i];
      float2 lv = *(const float2*)(el + (size_t)s*2);
      float v0 = lv.x + erv.x, v1 = lv.y + erv.y;
      v0 = (v0 > 0.f) ? v0 : 0.2f*v0;
      v1 = (v1 > 0.f) ? v1 : 0.2f*v1;
      s0 += fexp(v0 - m0); s1 += fexp(v1 - m1);
    }
    for (int k = 1; k < 64; k <<= 1){ s0 += __shfl_xor(s0, k); s1 += __shfl_xor(s1, k); }
    inv0 = (s0 > 0.f) ? 1.f/s0 : 0.f;
    inv1 = (s1 > 0.f) ? 1.f/s1 : 0.f;
    for (int c0 = e0; c0 < e1; c0 += 64){
      int ce = e1 - c0; if (ce > 64) ce = 64;
      if (lane < ce){
        int s = srcP[c0 + lane];
        float2 lv = *(const float2*)(el + (size_t)s*2);
        float v0 = lv.x + erv.x, v1 = lv.y + erv.y;
        v0 = (v0 > 0.f) ? v0 : 0.2f*v0;
        v1 = (v1 > 0.f) ? v1 : 0.2f*v1;
        ss[wave][lane] = s;
        sw[wave][lane][0] = fexp(v0 - m0);
        sw[wave][lane][1] = fexp(v1 - m1);
      }
      for (int i = quarter; i < ce; i += 4){
        int s = ss[wave][i];
        float w = sw[wave][i][head];
        uint4 hv = *(const uint4*)(hpair8 + (size_t)s*256 + sub*16);
        float2v wv = { w, w };
        acc[0] += wv*__builtin_amdgcn_cvt_pk_f32_fp8(hv.x, false);
        acc[1] += wv*__builtin_amdgcn_cvt_pk_f32_fp8(hv.x, true);
        acc[2] += wv*__builtin_amdgcn_cvt_pk_f32_fp8(hv.y, false);
        acc[3] += wv*__builtin_amdgcn_cvt_pk_f32_fp8(hv.y, true);
        acc[4] += wv*__builtin_amdgcn_cvt_pk_f32_fp8(hv.z, false);
        acc[5] += wv*__builtin_amdgcn_cvt_pk_f32_fp8(hv.z, true);
        acc[6] += wv*__builtin_amdgcn_cvt_pk_f32_fp8(hv.w, false);
        acc[7] += wv*__builtin_amdgcn_cvt_pk_f32_fp8(hv.w, true);
      }
    }
  }

  float inv = head ? inv1 : inv0;
  #pragma unroll
  for (int k = 0; k < 8; k++){
    float2v t16, t32;
    t16[0] = __shfl_xor(acc[k][0], 16); t16[1] = __shfl_xor(acc[k][1], 16);
    acc[k] += t16;
    t32[0] = __shfl_xor(acc[k][0], 32); t32[1] = __shfl_xor(acc[k][1], 32);
    acc[k] += t32;
  }
  float t[16];
  #pragma unroll
  for (int k = 0; k < 16; k++)
    t[k] = fmaxf(acc[k>>1][k&1]*inv + bias[sub*16 + k], 0.f);
  float o[16];
  #pragma unroll
  for (int k = 0; k < 16; k++) o[k] = 0.5f*(t[k] + __shfl_xor(t[k], 8));
  if (lane < 8){
    ushort u[16];
    #pragma unroll
    for (int k = 0; k < 16; k++) u[k] = (ushort)f2bf_rne(o[k]);
    *(uint4*)(outh + (size_t)n*128 + sub*16)     = *(uint4*)u;
    *(uint4*)(outh + (size_t)n*128 + sub*16 + 8) = *(uint4*)(u + 8);
    float gp = 0.f;
    #pragma unroll
    for (int k = 0; k < 16; k++) gp += o[k]*gwv[sub*16 + k];
    #pragma unroll
    for (int d = 1; d < 8; d <<= 1) gp += __shfl_xor(gp, d);
    if (sub == 0) gateOut[n] = gp + gbv[0];
  }
}

// ---------------- fused LSTM: seq = reduce(partials4), 2 layers x 4 steps + final head ----------------
__global__ __launch_bounds__(512) void k_lstm_all(const float* __restrict__ part4,
    const unsigned* __restrict__ Wxp, const unsigned* __restrict__ Whp,
    const float* __restrict__ bias2,
    const float* __restrict__ cw, const float* __restrict__ cb,
    float* __restrict__ out, int B){
  int b = blockIdx.x;
  int j = threadIdx.x;
  __shared__ float xs[4][128];
  __shared__ float gates[512];
  __shared__ float hcur[128], ccur[128];
  __shared__ float l0out[4][128];
  __shared__ float red[2];

  #pragma unroll
  for (int l = 0; l < 2; l++){
    const unsigned* Wx = Wxp + (size_t)l*32768;
    const unsigned* Wh = Whp + (size_t)l*32768;
    const float* bi = bias2 + l*512;
    { int t = j >> 7, k = j & 127;
      if (l == 0){
        const float* pp = part4 + (((size_t)t*B + b)*32)*128 + k;
        float s = 0.f;
        #pragma unroll
        for (int p2 = 0; p2 < 32; p2++) s += pp[p2*128];
        xs[t][k] = s;
      } else {
        xs[t][k] = l0out[t][k];
      }
      if (j < 128){ hcur[j] = 0.f; ccur[j] = 0.f; } }
    __syncthreads();
    float gx[4] = {0.f, 0.f, 0.f, 0.f};
    #pragma unroll 8
    for (int c = 0; c < 64; c++){
      unsigned w2 = Wx[c*512 + j];
      float wlo = __uint_as_float(w2 << 16);
      float whi = __uint_as_float(w2 & 0xffff0000u);
      #pragma unroll
      for (int t = 0; t < 4; t++)
        gx[t] += xs[t][2*c]*wlo + xs[t][2*c+1]*whi;
    }
    #pragma unroll
    for (int t = 0; t < 4; t++){
      float g = gx[t] + bi[j];
      #pragma unroll 8
      for (int c = 0; c < 64; c++){
        unsigned w2 = Wh[c*512 + j];
        g += hcur[2*c]*__uint_as_float(w2 << 16)
           + hcur[2*c+1]*__uint_as_float(w2 & 0xffff0000u);
      }
      gates[j] = g;
      __syncthreads();
      if (j < 128){
        float gi = sigmoidf_(gates[j]);
        float gf = sigmoidf_(gates[128 + j]);
        float gg = tanhf(gates[256 + j]);
        float go = sigmoidf_(gates[384 + j]);
        float c2 = gf * ccur[j] + gi * gg;
        float h = go * tanhf(c2);
        ccur[j] = c2;
        hcur[j] = h;
        if (l == 0) l0out[t][j] = h;
      }
      __syncthreads();
    }
  }
  float p = (j < 128) ? hcur[j] * cw[j] : 0.f;
  if (j < 128){
    for (int k = 1; k < 64; k <<= 1) p += __shfl_xor(p, k);
    if ((j & 63) == 0) red[j >> 6] = p;
  }
  __syncthreads();
  if (j == 0) out[b] = sigmoidf_(red[0] + red[1] + cb[0]);
}

extern "C" void kernel_launch(void* const* d_in, const int* in_sizes, int n_in,
                              void* d_out, int out_size, void* d_ws, size_t ws_size,
                              hipStream_t stream){
  const float* nfeats = (const float*)d_in[0];
  const int*   src    = (const int*)d_in[1];
  const int*   dst    = (const int*)d_in[2];
  const int*   ng     = (const int*)d_in[3];
  const float* Wm[3]  = { (const float*)d_in[4],  (const float*)d_in[8],  (const float*)d_in[12] };
  const float* al[3]  = { (const float*)d_in[5],  (const float*)d_in[9],  (const float*)d_in[13] };
  const float* ar[3]  = { (const float*)d_in[6],  (const float*)d_in[10], (const float*)d_in[14] };
  const float* bb[3]  = { (const float*)d_in[7],  (const float*)d_in[11], (const float*)d_in[15] };
  const float* gw[4]  = { (const float*)d_in[16], (const float*)d_in[18], (const float*)d_in[20], (const float*)d_in[22] };
  const float* gb[4]  = { (const float*)d_in[17], (const float*)d_in[19], (const float*)d_in[21], (const float*)d_in[23] };
  const float* Wih = (const float*)d_in[24];
  const float* Whh = (const float*)d_in[25];
  const float* bih = (const float*)d_in[26];
  const float* bhh = (const float*)d_in[27];
  const float* cw  = (const float*)d_in[28];
  const float* cb  = (const float*)d_in[29];

  const int N = in_sizes[3];      // 50000
  const int E = in_sizes[1];      // 800000
  const int B = out_size;         // 64

  char* p = (char*)d_ws;
  auto alloc = [&](size_t bytes) -> void* {
    void* q = (void*)p;
    p += (bytes + 255) & ~(size_t)255;
    return q;
  };
  unsigned char* hpair8 = (unsigned char*)alloc((size_t)N*256);
  ushort* agghA  = (ushort*)alloc((size_t)N*128*2);
  ushort* agghB  = (ushort*)alloc((size_t)N*128*2);
  ushort* xh0    = (ushort*)alloc((size_t)N*128*2);
  ushort* Wt     = (ushort*)alloc((size_t)3*256*128*2);
  float*  el     = (float*)alloc((size_t)N*2*4);
  float*  er     = (float*)alloc((size_t)N*2*4);
  int*    srcP   = (int*)alloc((size_t)E*4);
  float*  gateA  = (float*)alloc((size_t)N*4);
  float*  gateB  = (float*)alloc((size_t)N*4);
  int*    deg    = (int*)alloc((size_t)N*4);
  int*    cnt    = (int*)alloc((size_t)N*4);     // adjacent to deg: one memset
  int*    offs   = (int*)alloc((size_t)(N+1)*4);
  int*    gstart = (int*)alloc((size_t)(B+1)*4);
  int*    csum   = (int*)alloc((size_t)64*4);
  float*  part4  = (float*)alloc((size_t)4*B*32*128*4);   // 4 pool stages
  unsigned* Wxp  = (unsigned*)alloc((size_t)2*64*512*4);
  unsigned* Whp  = (unsigned*)alloc((size_t)2*64*512*4);
  float*  bias2  = (float*)alloc((size_t)2*512*4);

  auto cdiv = [](int a, int b){ return (a + b - 1) / b; };
  const int NB = cdiv(N, CHUNK);   // 49 chunks

  hipMemsetAsync(deg, 0, (size_t)((char*)cnt - (char*)deg) + (size_t)N*4, stream);
  k_hist<<<cdiv(E,256), 256, 0, stream>>>(dst, deg, E);
  k_chunksum<<<NB, 256, 0, stream>>>(deg, csum, N);
  k_scan_apply<<<NB, 256, 0, stream>>>(deg, csum, offs, N, NB);
  k_scatter_src<<<cdiv(E,256), 256, 0, stream>>>(src, dst, offs, cnt, srcP, E);

  {
    int nbGB = cdiv(N,256), nbTG = cdiv(N,4), nbWT = (3*256*128)/256, nbLP = cdiv(131072,256);
    k_prep<<<nbGB + nbTG + nbWT + nbLP, 256, 0, stream>>>(
        ng, gstart, nfeats, gw[0], gb[0], xh0, gateA,
        Wm[0], Wm[1], Wm[2], Wt, Wih, Whh, bih, bhh, Wxp, Whp, bias2, N, B);
  }

  const int strips = cdiv(N, 16);
  const int gemmBlocks = cdiv(strips, 4);   // 782
  const int aggBlocks  = cdiv(N, 4);        // 12500
  const int poolBlocks = B*16;              // 1024

  // ping-pong: stage t pool reads (x_t, gate_t); aggregate t writes (x_{t+1}, gate_{t+1})
  const ushort* xs[4]  = { xh0, agghA, agghB, agghA };
  ushort*       xo[3]  = { agghA, agghB, agghA };
  float*        gs[4]  = { gateA, gateB, gateA, gateB };
  float*        go[3]  = { gateB, gateA, gateB };

  for (int layer = 0; layer < 3; layer++){
    k_gemm_mfma<<<gemmBlocks, 256, 0, stream>>>(xs[layer], Wt + (size_t)layer*256*128,
        al[layer], ar[layer], hpair8, el, er, N);
    // aggregate layer + riding pool stage `layer` (reads prev-stage buffers)
    k_agg_pool<<<aggBlocks + poolBlocks, 256, 0, stream>>>(hpair8, el, er, srcP, offs,
        bb[layer], gw[layer+1], gb[layer+1], xo[layer], go[layer], N, aggBlocks,
        xs[layer], gs[layer], gstart, part4 + (size_t)layer*B*32*128);
  }
  // pool stage 3 alone (aggregate role empty)
  k_agg_pool<<<poolBlocks, 256, 0, stream>>>(hpair8, el, er, srcP, offs,
      bb[0], gw[0], gb[0], agghB, gateA, 0, 0,
      xs[3], gs[3], gstart, part4 + (size_t)3*B*32*128);

  k_lstm_all<<<B, 512, 0, stream>>>(part4, Wxp, Whp, bias2, cw, cb, (float*)d_out, B);
}